// Round 10
// baseline (280.576 us; speedup 1.0000x reference)
//
#include <hip/hip_runtime.h>
#include <hip/hip_fp16.h>

typedef _Float16 half_t;
typedef _Float16 half4 __attribute__((ext_vector_type(4)));
typedef _Float16 half8 __attribute__((ext_vector_type(8)));
typedef float floatx4 __attribute__((ext_vector_type(4)));

static constexpr int BATCH = 2;
static constexpr int NSP = 4096;   // H*W
static constexpr int CH = 512;
static constexpr int NQKV = 3 * CH;  // 1536
static constexpr int KSPLIT = 4;
static constexpr float QSCALE = 0.044194173824159216f;  // 1/sqrt(512)

// ---- ws layout (bytes) ----
static constexpr size_t OFF_STATS = 0;                              // 128 f32
static constexpr size_t OFF_ROWSUM = 512;                           // B*NSP f32 (32 KB)
static constexpr size_t OFF_B2 = 33280;                             // 2*1536 f32 (12 KB)
static constexpr size_t OFF_PST = 45568;                            // GN partials 128 KB
static constexpr size_t OFF_W2 = 196608;                            // scaled qkv weights [2][1536][512] f16 = 3 MB
static constexpr size_t OFF_WP = OFF_W2 + (size_t)2 * NQKV * CH * 2;
static constexpr size_t OFF_X16 = OFF_WP + (size_t)CH * CH * 2;     // x cast f16, 8 MB
static constexpr size_t XN_BYTES = (size_t)BATCH * NSP * CH * 2;    // 8 MB
static constexpr size_t OFF_QKV = OFF_X16 + XN_BYTES;
static constexpr size_t QKV_BYTES = (size_t)BATCH * NSP * NQKV * 2; // 24 MB
static constexpr size_t OFF_VT = OFF_QKV + QKV_BYTES;
static constexpr size_t OFF_AO = OFF_VT + XN_BYTES;
static constexpr size_t OFF_S = OFF_AO + XN_BYTES;
static constexpr size_t S_BYTES_1 = (size_t)NSP * NSP * 2;          // 32 MB / batch
// PV split-K partials: 8 slabs x 4 MB = 32 MB, overlay x16+qkv (dead by PV)
static constexpr size_t OFF_PART = OFF_X16;

__device__ __forceinline__ void gld16(void* lds, const void* g) {
  __builtin_amdgcn_global_load_lds(
      (__attribute__((address_space(1))) void*)(g),
      (__attribute__((address_space(3))) void*)(lds),
      16, 0, 0);
}

// ---------------- GN stage 1: cast x->f16 AND write group partials ----------
__global__ __launch_bounds__(256) void gn_cast_stats(const float* __restrict__ x,
                                                     half_t* __restrict__ x16,
                                                     float* __restrict__ pst) {
  int b = blockIdx.y;
  int tid = (int)threadIdx.x;
  int g = ((tid * 8) & (CH - 1)) >> 4;  // 8-span never crosses 16-ch group
  long base = (long)b * NSP * CH + (long)blockIdx.x * 16 * CH + tid * 8;
  float s = 0.f, s2 = 0.f;
#pragma unroll
  for (int it = 0; it < 4; ++it) {
    long idx = base + (long)it * 2048;
    floatx4 a = *(const floatx4*)(x + idx);
    floatx4 d = *(const floatx4*)(x + idx + 4);
    half8 o;
#pragma unroll
    for (int r = 0; r < 4; ++r) {
      s += a[r] + d[r];
      s2 += a[r] * a[r] + d[r] * d[r];
      o[r] = (half_t)a[r];
      o[r + 4] = (half_t)d[r];
    }
    *(half8*)(x16 + idx) = o;
  }
  __shared__ float gs[32], gs2[32];
  if (tid < 32) { gs[tid] = 0.f; gs2[tid] = 0.f; }
  __syncthreads();
  atomicAdd(&gs[g], s);
  atomicAdd(&gs2[g], s2);
  __syncthreads();
  if (tid < 32) {
    long idx = ((long)(b * 256 + blockIdx.x) * 32 + tid) * 2;
    pst[idx] = gs[tid];
    pst[idx + 1] = gs2[tid];
  }
}

// ---------------- GN stage 2: reduce -> mean/rstd; zero rowsum -------------
__global__ __launch_bounds__(256) void gn_finalize(const float* __restrict__ pst,
                                                   float* __restrict__ st,
                                                   float* __restrict__ rowsum) {
  int tid = (int)threadIdx.x;
  int bg = tid & 63;
  int p = tid >> 6;
  int b = bg >> 5, g = bg & 31;
  float s = 0.f, s2 = 0.f;
  for (int j = 0; j < 64; ++j) {
    int chunk = p * 64 + j;
    long idx = ((long)(b * 256 + chunk) * 32 + g) * 2;
    s += pst[idx];
    s2 += pst[idx + 1];
  }
  __shared__ float rs[64][4], rs2[64][4];
  rs[bg][p] = s;
  rs2[bg][p] = s2;
  __syncthreads();
  if (tid < 64) {
    float ts = rs[tid][0] + rs[tid][1] + rs[tid][2] + rs[tid][3];
    float ts2 = rs2[tid][0] + rs2[tid][1] + rs2[tid][2] + rs2[tid][3];
    const float inv = 1.f / 65536.f;
    float mean = ts * inv;
    float var = ts2 * inv - mean * mean;
    st[tid * 2] = mean;
    st[tid * 2 + 1] = rsqrtf(var + 1e-5f);
  }
  floatx4* rz = (floatx4*)rowsum;
#pragma unroll
  for (int j = 0; j < 8; ++j)
    rz[tid + j * 256] = floatx4{0.f, 0.f, 0.f, 0.f};
}

// ---- transpose + GN-scale weights: W2[b][z*512+d][c] = w[c,d]*rstd*gamma ----
__global__ __launch_bounds__(256) void transpose_w(
    const float* __restrict__ w0, const float* __restrict__ w1,
    const float* __restrict__ w2, const float* __restrict__ w3,
    half_t* __restrict__ wqkv2, half_t* __restrict__ wpT,
    const float* __restrict__ st, const float* __restrict__ gamma) {
  int z = blockIdx.z;
  const float* w;
  switch (z) {
    case 0: w = w0; break;
    case 1: w = w1; break;
    case 2: w = w2; break;
    default: w = w3; break;
  }
  __shared__ float t[32][33];
  int d0 = blockIdx.x * 32, c0 = blockIdx.y * 32;
  int tx = threadIdx.x & 31, ty = threadIdx.x >> 5;
#pragma unroll
  for (int i = 0; i < 4; ++i)
    t[ty + i * 8][tx] = w[(long)(c0 + ty + i * 8) * CH + d0 + tx];
  __syncthreads();
  if (z == 3) {
#pragma unroll
    for (int i = 0; i < 4; ++i) {
      int d = ty + i * 8;
      wpT[(long)(d0 + d) * CH + c0 + tx] = (half_t)t[tx][d];
    }
  } else {
    int c = c0 + tx, g = c >> 4;
    float qs = (z == 0) ? QSCALE : 1.f;
#pragma unroll
    for (int b = 0; b < BATCH; ++b) {
      float sfac = st[((b << 5) + g) * 2 + 1] * gamma[c] * qs;
#pragma unroll
      for (int i = 0; i < 4; ++i) {
        int d = ty + i * 8;
        wqkv2[(long)b * NQKV * CH + (long)(z * CH + d0 + d) * CH + c] =
            (half_t)(t[tx][d] * sfac);
      }
    }
  }
}

// ---- effective biases: b2[b][d] = (bias_d + sum_c coef[b][c]*w[c,d]) * qs ----
__global__ __launch_bounds__(256) void bias_prep(
    const float* __restrict__ wq, const float* __restrict__ wk,
    const float* __restrict__ wv, const float* __restrict__ bq,
    const float* __restrict__ bk, const float* __restrict__ bv,
    const float* __restrict__ st, const float* __restrict__ gamma,
    const float* __restrict__ beta, float* __restrict__ b2) {
  int d = blockIdx.x * 256 + (int)threadIdx.x;  // 0..1535
  int b = blockIdx.y;
  int wi = d >> 9, dd = d & 511;
  const float* w = wi == 0 ? wq : (wi == 1 ? wk : wv);
  const float* bias = wi == 0 ? bq : (wi == 1 ? bk : bv);
  float acc = 0.f;
  for (int c = 0; c < CH; ++c) {
    int g = c >> 4;
    float mean = st[((b << 5) + g) * 2];
    float rstd = st[((b << 5) + g) * 2 + 1];
    float coef = beta[c] - mean * rstd * gamma[c];
    acc += coef * w[(long)c * CH + dd];
  }
  float r = bias[dd] + acc;
  if (wi == 0) r *= QSCALE;
  b2[b * NQKV + d] = r;
}

// ---------------- NT GEMM: C[M,N] = X[M,K] * Y[N,K]^T ----------------
// R6 structure (single LDS buffer, 2 barriers/iter) + hoisted addresses
// (validated R8/R9). LDS chunk swizzle on global side; 0 bank conflicts.
// SWZ: 1 = window-256 XCD swizzle (scores); 2 = m-major x/y swap (A-panel
//      sharers lin%8-equal -> same XCD).
// KSP: split-K; blockIdx.z = b*KSP+ks; X/Y advance ks*K; C slab = z*cbs.
// EPI: 0 = plain half store (PV partials)
//      1 = QKV: +b0[zb*NQKV+gn]; n0>=1024 -> transposed store into aux (vt)
//      2 = +b0 +resid, float store
//      3 = scores: store exp(acc) half + atomicAdd row sums into rowsum
template <int BM, int BN, int BK, int EPI, int SWZ, int KSP, typename OutT>
__global__ __launch_bounds__(256) void gemm_nt(
    const half_t* __restrict__ X, const half_t* __restrict__ Y,
    OutT* __restrict__ Co, const float* __restrict__ b0,
    const float* __restrict__ resid, float* __restrict__ rowsum,
    half_t* __restrict__ aux,
    int M, int N, int K, int ldx, int ldy, int ldc,
    long xbs, long ybs, long cbs) {
  constexpr int SM = BM / 32;
  constexpr int SN = BN / 32;
  constexpr int ROWS = BM + BN;
  constexpr int CPR = BK / 8;
  constexpr int RPW = 64 / CPR;
  constexpr int ROUNDS = (ROWS * BK * 2) / 4096;
  constexpr int KSTEPS = BK / 32;
  constexpr int LDSH = (EPI == 1 && ROWS * BK < 17408) ? 17408 : ROWS * BK;
  static_assert(BM % (4 * RPW) == 0, "no As/Bs straddle within a round");
  __shared__ __align__(16) half_t Sh[LDSH];

  const int zb = blockIdx.z / KSP;
  const int ks = blockIdx.z % KSP;
  int bx, by;
  if (SWZ == 1) {
    int lin = (int)(blockIdx.x + gridDim.x * blockIdx.y);
    int wmt = 256 / (int)gridDim.x;
    by = wmt * (lin >> 8) + ((lin & 255) % wmt);
    bx = (lin & 255) / wmt;
  } else if (SWZ == 2) {
    by = blockIdx.x;   // m-major
    bx = blockIdx.y;
  } else {
    bx = blockIdx.x;
    by = blockIdx.y;
  }

  const half_t* Xb = X + (long)zb * xbs + (long)ks * K;
  const half_t* Yb = Y + (long)zb * ybs + (long)ks * K;
  OutT* Cb = Co + (long)blockIdx.z * cbs;

  const int m0 = by * BM;
  const int n0 = bx * BN;
  const int tid = (int)threadIdx.x;
  const int wave = tid >> 6;
  const int lane = tid & 63;
  const int quad = lane >> 4;
  const int l16 = lane & 15;
  const int wm = wave >> 1;
  const int wn = wave & 1;

  floatx4 acc[SM][SN] = {};

  const int srow = lane / CPR;
  const int schunk = lane % CPR;
  const char* Xc = (const char*)Xb;

  int soff[ROUNDS];
#pragma unroll
  for (int r = 0; r < ROUNDS; ++r) {
    int row = r * (4 * RPW) + wave * RPW + srow;
    int gchunk = schunk ^ (row & (CPR - 1));
    const char* p = (row < BM)
        ? (const char*)(Xb + (long)(m0 + row) * ldx)
        : (const char*)(Yb + (long)(n0 + row - BM) * ldy);
    soff[r] = (int)(p + gchunk * 16 - Xc);
  }

  int offA[SM], offB[SN];
#pragma unroll
  for (int i = 0; i < SM; ++i) {
    int m = wm * (BM / 2) + i * 16 + l16;
    int cc = quad ^ (m & (CPR - 1));
    offA[i] = (m * BK + cc * 8) * 2;
  }
#pragma unroll
  for (int j = 0; j < SN; ++j) {
    int n = wn * (BN / 2) + j * 16 + l16;
    int cc = quad ^ (n & (CPR - 1));
    offB[j] = (BM * BK + n * BK + cc * 8) * 2;
  }

  for (int k0 = 0; k0 < K; k0 += BK) {
#pragma unroll
    for (int r = 0; r < ROUNDS; ++r) {
      gld16((char*)Sh + (r * 4 + wave) * 1024, Xc + (long)soff[r]);
      soff[r] += BK * 2;
    }
    __syncthreads();

#pragma unroll
    for (int kk = 0; kk < KSTEPS; ++kk) {
      const int kx = kk << 6;
      half8 af[SM], bf[SN];
#pragma unroll
      for (int i = 0; i < SM; ++i)
        af[i] = *(const half8*)((const char*)Sh + (offA[i] ^ kx));
#pragma unroll
      for (int j = 0; j < SN; ++j)
        bf[j] = *(const half8*)((const char*)Sh + (offB[j] ^ kx));
#pragma unroll
      for (int i = 0; i < SM; ++i)
#pragma unroll
        for (int j = 0; j < SN; ++j)
          acc[i][j] = __builtin_amdgcn_mfma_f32_16x16x32_f16(af[i], bf[j], acc[i][j], 0, 0, 0);
    }
    __syncthreads();
  }

  if (EPI == 1 && n0 >= 2 * CH) {
    // v tile: add bias, transpose via LDS (pad stride 136 -> 2-way max), store to vt
    constexpr int TP = 136;
#pragma unroll
    for (int i = 0; i < SM; ++i) {
      int mb = wm * (BM / 2) + i * 16 + quad * 4;
#pragma unroll
      for (int j = 0; j < SN; ++j) {
        int dl = wn * (BN / 2) + j * 16 + l16;
        float bias = b0[zb * NQKV + n0 + dl];
        half4 h;
#pragma unroll
        for (int r = 0; r < 4; ++r) h[r] = (half_t)(acc[i][j][r] + bias);
        *(half4*)(Sh + dl * TP + mb) = h;
      }
    }
    __syncthreads();
    int tx = tid & 15, ty = tid >> 4;
    half_t* vtb = aux + (long)zb * NSP * CH;
#pragma unroll
    for (int jj = 0; jj < 8; ++jj) {
      int d = ty + jj * 16;
      half8 h = *(const half8*)(Sh + d * TP + tx * 8);
      *(half8*)(vtb + (long)(n0 - 2 * CH + d) * NSP + m0 + tx * 8) = h;
    }
    return;
  }

#pragma unroll
  for (int i = 0; i < SM; ++i) {
    int gmb = m0 + wm * (BM / 2) + i * 16 + quad * 4;
    float rs[4] = {0.f, 0.f, 0.f, 0.f};
#pragma unroll
    for (int j = 0; j < SN; ++j) {
      int gn = n0 + wn * (BN / 2) + j * 16 + l16;
      float bias = 0.f;
      if (EPI == 1) bias = b0[zb * NQKV + gn];
      else if (EPI == 2) bias = b0[gn];
#pragma unroll
      for (int r = 0; r < 4; ++r) {
        long idx = (long)(gmb + r) * ldc + gn;
        float v = acc[i][j][r];
        if (EPI == 1) v += bias;
        if (EPI == 2) v = v + bias + resid[idx];
        if (EPI == 3) { v = __expf(v); rs[r] += v; }
        Cb[idx] = (OutT)v;
      }
    }
    if (EPI == 3) {
#pragma unroll
      for (int r = 0; r < 4; ++r) {
        float v = rs[r];
        v += __shfl_xor(v, 1);
        v += __shfl_xor(v, 2);
        v += __shfl_xor(v, 4);
        v += __shfl_xor(v, 8);
        if (l16 == 0) atomicAdd(&rowsum[(long)zb * NSP + gmb + r], v);
      }
    }
  }
}

// ---------------- PV split-K combine: ao = (sum of slabs) / rowsum --------
__global__ __launch_bounds__(256) void pv_combine(const half_t* __restrict__ part,
                                                  const float* __restrict__ rowsum,
                                                  half_t* __restrict__ ao) {
  const long bNC = (long)NSP * CH;
  long i = ((long)blockIdx.x * 256 + threadIdx.x) * 8;
  int b = (int)(i >> 21);
  long inner = i & ((1L << 21) - 1);
  float inv = 1.f / rowsum[i >> 9];
  float s[8] = {};
#pragma unroll
  for (int ks = 0; ks < KSPLIT; ++ks) {
    half8 h = *(const half8*)(part + ((long)(b * KSPLIT + ks)) * bNC + inner);
#pragma unroll
    for (int r = 0; r < 8; ++r) s[r] += (float)h[r];
  }
  half8 o;
#pragma unroll
  for (int r = 0; r < 8; ++r) o[r] = (half_t)(s[r] * inv);
  *(half8*)(ao + i) = o;
}

extern "C" void kernel_launch(void* const* d_in, const int* in_sizes, int n_in,
                              void* d_out, int out_size, void* d_ws, size_t ws_size,
                              hipStream_t stream) {
  const float* x = (const float*)d_in[0];
  const float* gamma = (const float*)d_in[1];
  const float* beta = (const float*)d_in[2];
  const float* wq = (const float*)d_in[3];
  const float* bq = (const float*)d_in[4];
  const float* wk = (const float*)d_in[5];
  const float* bk = (const float*)d_in[6];
  const float* wv = (const float*)d_in[7];
  const float* bv = (const float*)d_in[8];
  const float* wp = (const float*)d_in[9];
  const float* bp = (const float*)d_in[10];
  float* out = (float*)d_out;
  char* ws = (char*)d_ws;

  float* st = (float*)(ws + OFF_STATS);
  float* rsum = (float*)(ws + OFF_ROWSUM);
  float* b2 = (float*)(ws + OFF_B2);
  float* pst = (float*)(ws + OFF_PST);
  half_t* w2 = (half_t*)(ws + OFF_W2);       // [2][1536][512] GN-scaled
  half_t* wpT = (half_t*)(ws + OFF_WP);
  half_t* x16 = (half_t*)(ws + OFF_X16);
  half_t* qkv = (half_t*)(ws + OFF_QKV);     // [B][4096][1536] (v third unused)
  half_t* vt = (half_t*)(ws + OFF_VT);
  half_t* ao = (half_t*)(ws + OFF_AO);
  half_t* S = (half_t*)(ws + OFF_S);
  half_t* part = (half_t*)(ws + OFF_PART);

  half_t* q = qkv;            // ld NQKV
  half_t* k = qkv + CH;       // ld NQKV

  const long bQKV = (long)NSP * NQKV;
  const long bNC = (long)NSP * CH;
  const long bNN = (long)NSP * NSP;

  gn_cast_stats<<<dim3(256, BATCH), 256, 0, stream>>>(x, x16, pst);
  gn_finalize<<<1, 256, 0, stream>>>(pst, st, rsum);
  transpose_w<<<dim3(16, 16, 4), 256, 0, stream>>>(wq, wk, wv, wp, w2, wpT, st, gamma);
  bias_prep<<<dim3(6, BATCH), 256, 0, stream>>>(wq, wk, wv, bq, bk, bv, st, gamma, beta, b2);

  // qkv = x16 @ W2[b]^T + b2[b]; v third written transposed into vt
  gemm_nt<128, 128, 64, 1, 2, 1, half_t><<<dim3(NSP / 128, NQKV / 128, BATCH), 256, 0, stream>>>(
      x16, w2, qkv, b2, nullptr, nullptr, vt, NSP, NQKV, CH,
      CH, CH, NQKV, bNC, (long)NQKV * CH, bQKV);

  bool full = ws_size >= OFF_S + 2 * S_BYTES_1;
  if (full) {
    // scores -> exp(s) + row sums: 128x128 BK=64 + window swizzle, (32,32,2)
    gemm_nt<128, 128, 64, 3, 1, 1, half_t><<<dim3(32, 32, BATCH), 256, 0, stream>>>(
        q, k, S, nullptr, nullptr, rsum, nullptr, NSP, NSP, CH,
        NQKV, NQKV, NSP, bQKV, bQKV, bNN);
    // PV split-K: 128x128 BK=64, m-major, (32,4,8)
    gemm_nt<128, 128, 64, 0, 2, KSPLIT, half_t><<<dim3(NSP / 128, CH / 128, BATCH * KSPLIT), 256, 0, stream>>>(
        S, vt, part, nullptr, nullptr, nullptr, nullptr, NSP, CH, NSP / KSPLIT,
        NSP, NSP, CH, bNN, bNC, bNC);
    pv_combine<<<2048, 256, 0, stream>>>(part, rsum, ao);
  } else {
    for (int bb = 0; bb < BATCH; ++bb) {
      gemm_nt<128, 128, 64, 3, 1, 1, half_t><<<dim3(32, 32, 1), 256, 0, stream>>>(
          q + bb * bQKV, k + bb * bQKV, S, nullptr, nullptr, rsum + bb * NSP, nullptr,
          NSP, NSP, CH, NQKV, NQKV, NSP, 0, 0, 0);
      gemm_nt<128, 128, 64, 0, 2, KSPLIT, half_t><<<dim3(NSP / 128, CH / 128, KSPLIT), 256, 0, stream>>>(
          S, vt + bb * bNC, part + (long)bb * KSPLIT * bNC, nullptr, nullptr, nullptr,
          nullptr, NSP, CH, NSP / KSPLIT, NSP, NSP, CH, 0, 0, bNC);
    }
    pv_combine<<<2048, 256, 0, stream>>>(part, rsum, ao);
  }
  // out = ao @ wp^T + bp + x : 64x64 BK=128, m-major (128,8)
  gemm_nt<64, 64, 128, 2, 2, 1, float><<<dim3(BATCH * NSP / 64, CH / 64, 1), 256, 0, stream>>>(
      ao, wpT, out, bp, x, nullptr, nullptr, BATCH * NSP, CH, CH,
      CH, CH, CH, 0, 0, 0);
}